// Round 3
// baseline (189.490 us; speedup 1.0000x reference)
//
#include <hip/hip_runtime.h>
#include <math.h>

#define BB 4
#define LQ 2048
#define LK 2048
#define HD 8
#define VD 64
#define HV 512
#define SP 72   // padded LDS row stride (bf16 elems): 144 B, 16B-aligned

typedef __attribute__((ext_vector_type(8))) short bf16x8;
typedef __attribute__((ext_vector_type(4))) float f32x4;

static __device__ __forceinline__ unsigned short f2bf(float f) {  // RNE
    unsigned u = __builtin_bit_cast(unsigned, f);
    unsigned r = (u + 0x7fffu + ((u >> 16) & 1u)) >> 16;
    return (unsigned short)r;
}

static __device__ __forceinline__ float fast_exp2(float x) {
#if __has_builtin(__builtin_amdgcn_exp2f)
    return __builtin_amdgcn_exp2f(x);
#else
    return __expf(x * 0.69314718f);
#endif
}

// pack hi16(a_even), hi16(a_odd) -> one dword (bf16 truncation x2, 1 VALU op)
static __device__ __forceinline__ unsigned pack_trunc(float even, float odd) {
    return __builtin_amdgcn_perm(__builtin_bit_cast(unsigned, odd),
                                 __builtin_bit_cast(unsigned, even), 0x07060302u);
}

// ---------------- values fp32 [b][k][h][v] -> bf16 [b][h][v][k] ----------------
__global__ __launch_bounds__(256) void cvt_vals(
    const float* __restrict__ vals, unsigned short* __restrict__ vals_t)
{
    __shared__ unsigned short st[64 * SP];   // [v][k] tile
    const int tid = threadIdx.x;
    const int kt = blockIdx.x, h = blockIdx.y, b = blockIdx.z;

    const int k  = tid >> 2;
    const int vb = (tid & 3) * 16;
    const float* src = vals + (((size_t)(b * LK + kt * 64 + k) * HD + h)) * VD + vb;
    float4 f0 = *(const float4*)(src);
    float4 f1 = *(const float4*)(src + 4);
    float4 f2 = *(const float4*)(src + 8);
    float4 f3 = *(const float4*)(src + 12);
    const float fv[16] = {f0.x,f0.y,f0.z,f0.w, f1.x,f1.y,f1.z,f1.w,
                          f2.x,f2.y,f2.z,f2.w, f3.x,f3.y,f3.z,f3.w};
#pragma unroll
    for (int j = 0; j < 16; ++j) st[(vb + j) * SP + k] = f2bf(fv[j]);
    __syncthreads();

    const int v  = tid >> 2;
    const int kb = (tid & 3) * 16;
    uint4 o0 = *(const uint4*)&st[v * SP + kb];
    uint4 o1 = *(const uint4*)&st[v * SP + kb + 8];
    unsigned short* dst = vals_t + ((size_t)((b * HD + h) * VD + v)) * LK + kt * 64 + kb;
    *(uint4*)dst       = o0;
    *(uint4*)(dst + 8) = o1;
}

// ---------------- W fp32 [512][512] -> bf16 ----------------
__global__ __launch_bounds__(256) void cvt_w(
    const float* __restrict__ w, unsigned short* __restrict__ wb)
{
    const int i = (blockIdx.x * 256 + threadIdx.x) * 4;
    float4 f = *(const float4*)(w + i);
    ushort4 o;
    o.x = f2bf(f.x); o.y = f2bf(f.y); o.z = f2bf(f.z); o.w = f2bf(f.w);
    *(ushort4*)(wb + i) = o;
}

// ---------------- fused gaussian attention: d2 shared, A-frags in regs ----------------
// grid (qt=32, hs=2, b=4); 256 thr; wave w -> head hs*4+w, q-strips 0..3 (16 q each)
__global__ __launch_bounds__(256, 1) void attend3(
    const float* __restrict__ qpos,
    const float* __restrict__ kpos,
    const unsigned short* __restrict__ vals_t,
    const int*   __restrict__ kmask,
    const float* __restrict__ ls,
    unsigned short* __restrict__ attended)
{
    __shared__ __align__(16) unsigned short sV[2][256 * SP];  // [buf][(wave*64+v)][k] wave-local
    __shared__ __align__(16) float skx[2][64], sky[2][64], skz[2][64];

    const int tid  = threadIdx.x;
    const int qt = blockIdx.x, hs = blockIdx.y, b = blockIdx.z;
    const int q0 = qt * 64;
    const int wave = tid >> 6, lane = tid & 63;
    const int ln = lane & 15, kq = lane >> 4;
    const int h = hs * 4 + wave;

    const float lsh = ls[h];
    const float ch  = -1.44269504f / (lsh * lsh);   // exp(-d2/ls^2) = exp2(ch*d2)

    // q positions for this lane's 4 q-strips
    float qx[4], qy[4], qz[4];
#pragma unroll
    for (int qs = 0; qs < 4; ++qs) {
        const float* qp = qpos + (size_t)(b * LQ + q0 + qs * 16 + ln) * 3;
        qx[qs] = qp[0]; qy[qs] = qp[1]; qz[qs] = qp[2];
    }

    // V staging: thread stages row (wave=head, v=lane) of its own wave's head
    const unsigned short* vsrc = vals_t + (size_t)((b * HD + h) * VD + lane) * LK;

    // ---- prologue: stage tile 0 ----
    uint4 vreg[8];
    float kxr = 0.f, kyr = 0.f, kzr = 0.f;
#pragma unroll
    for (int j = 0; j < 8; ++j) vreg[j] = ((const uint4*)vsrc)[j];
    if (tid < 64) {
        const int idx = b * LK + tid;
        kxr = kpos[(size_t)idx * 3];
        kyr = kpos[(size_t)idx * 3 + 1];
        kzr = kpos[(size_t)idx * 3 + 2];
        if (kmask[idx]) kxr = 3.0e37f;   // d2 -> ~9e74 -> exp2 -> 0
    }
    {
        unsigned short* d = &sV[0][tid * SP];
#pragma unroll
        for (int j = 0; j < 8; ++j) *(uint4*)(d + j * 8) = vreg[j];
        if (tid < 64) { skx[0][tid] = kxr; sky[0][tid] = kyr; skz[0][tid] = kzr; }
    }
    __syncthreads();

    f32x4 acc[4][4];   // [qs][vt]
#pragma unroll
    for (int i = 0; i < 4; ++i)
#pragma unroll
        for (int j = 0; j < 4; ++j) acc[i][j] = (f32x4){0.f, 0.f, 0.f, 0.f};
    float pden[4] = {0.f, 0.f, 0.f, 0.f};

    for (int t = 0; t < 32; ++t) {
        const int cur = t & 1;
        const int tn  = (t < 31) ? t + 1 : 0;   // last iter: dummy re-stage of tile 0

        // ---- prefetch next tile (global -> regs), hidden under compute ----
        {
            const unsigned short* s = vsrc + tn * 64;
#pragma unroll
            for (int j = 0; j < 8; ++j) vreg[j] = ((const uint4*)s)[j];
        }
        if (tid < 64) {
            const int idx = b * LK + tn * 64 + tid;
            kxr = kpos[(size_t)idx * 3];
            kyr = kpos[(size_t)idx * 3 + 1];
            kzr = kpos[(size_t)idx * 3 + 2];
            if (kmask[idx]) kxr = 3.0e37f;
        }

        // ---- B fragments for this tile (wave-local LDS rows), reused over 4 q-strips ----
        bf16x8 bfrag[4][2];
#pragma unroll
        for (int vt = 0; vt < 4; ++vt) {
            const unsigned short* bp = &sV[cur][(wave * 64 + vt * 16 + ln) * SP + kq * 8];
            bfrag[vt][0] = *(const bf16x8*)(bp);
            bfrag[vt][1] = *(const bf16x8*)(bp + 32);
        }

        // ---- this lane's 16 k coordinates: k = kq*8+j and 32+kq*8+j ----
        float kxa[16], kya[16], kza[16];
        *(float4*)&kxa[0]  = *(const float4*)&skx[cur][kq * 8];
        *(float4*)&kxa[4]  = *(const float4*)&skx[cur][kq * 8 + 4];
        *(float4*)&kxa[8]  = *(const float4*)&skx[cur][kq * 8 + 32];
        *(float4*)&kxa[12] = *(const float4*)&skx[cur][kq * 8 + 36];
        *(float4*)&kya[0]  = *(const float4*)&sky[cur][kq * 8];
        *(float4*)&kya[4]  = *(const float4*)&sky[cur][kq * 8 + 4];
        *(float4*)&kya[8]  = *(const float4*)&sky[cur][kq * 8 + 32];
        *(float4*)&kya[12] = *(const float4*)&sky[cur][kq * 8 + 36];
        *(float4*)&kza[0]  = *(const float4*)&skz[cur][kq * 8];
        *(float4*)&kza[4]  = *(const float4*)&skz[cur][kq * 8 + 4];
        *(float4*)&kza[8]  = *(const float4*)&skz[cur][kq * 8 + 32];
        *(float4*)&kza[12] = *(const float4*)&skz[cur][kq * 8 + 36];

        // ---- scores in A-frag layout + MFMA ----
#pragma unroll
        for (int qs = 0; qs < 4; ++qs) {
            float s[16];
#pragma unroll
            for (int j = 0; j < 16; ++j) {
                const float dx = qx[qs] - kxa[j];
                const float dy = qy[qs] - kya[j];
                const float dz = qz[qs] - kza[j];
                const float d2 = fmaf(dx, dx, fmaf(dy, dy, dz * dz));
                const float sc = fast_exp2(d2 * ch);
                pden[qs] += sc;
                s[j] = sc;
            }
            unsigned pk[8];
#pragma unroll
            for (int p = 0; p < 8; ++p) pk[p] = pack_trunc(s[2 * p], s[2 * p + 1]);
            const bf16x8 a0 = __builtin_bit_cast(bf16x8, *(uint4*)&pk[0]);
            const bf16x8 a1 = __builtin_bit_cast(bf16x8, *(uint4*)&pk[4]);
#pragma unroll
            for (int vt = 0; vt < 4; ++vt) {
                acc[qs][vt] = __builtin_amdgcn_mfma_f32_16x16x32_bf16(a0, bfrag[vt][0], acc[qs][vt], 0, 0, 0);
                acc[qs][vt] = __builtin_amdgcn_mfma_f32_16x16x32_bf16(a1, bfrag[vt][1], acc[qs][vt], 0, 0, 0);
            }
        }

        // ---- write prefetched tile into other buffer ----
        {
            const int nb = tn & 1;
            unsigned short* d = &sV[nb][tid * SP];
#pragma unroll
            for (int j = 0; j < 8; ++j) *(uint4*)(d + j * 8) = vreg[j];
            if (tid < 64) { skx[nb][tid] = kxr; sky[nb][tid] = kyr; skz[nb][tid] = kzr; }
        }
        __syncthreads();
    }

    // ---- denominator: reduce over kq lane-groups, distribute to C-layout rows ----
    float inv[4];
#pragma unroll
    for (int qs = 0; qs < 4; ++qs) {
        float v = pden[qs];
        v += __shfl_xor(v, 16, 64);
        v += __shfl_xor(v, 32, 64);
        inv[qs] = 1.0f / (v + 1e-5f);      // den for q = qs*16 + ln
    }
    float ivq[4][4];
#pragma unroll
    for (int qs = 0; qs < 4; ++qs)
#pragma unroll
        for (int r = 0; r < 4; ++r) ivq[qs][r] = __shfl(inv[qs], kq * 4 + r, 64);

#pragma unroll
    for (int qs = 0; qs < 4; ++qs)
#pragma unroll
        for (int vt = 0; vt < 4; ++vt)
#pragma unroll
            for (int r = 0; r < 4; ++r) {
                const int q = q0 + qs * 16 + kq * 4 + r;
                attended[(size_t)(b * LQ + q) * HV + h * VD + vt * 16 + ln] =
                    f2bf(acc[qs][vt][r] * ivq[qs][r]);
            }
}

// ---------------- projection: C[8192][512] = A_bf16 @ Wb^T, 128x128 tiles ----------------
__global__ __launch_bounds__(256, 1) void proj3(
    const unsigned short* __restrict__ A,
    const unsigned short* __restrict__ Wb,
    float* __restrict__ C)
{
    __shared__ __align__(16) unsigned short sA[128 * SP];
    __shared__ __align__(16) unsigned short sW[128 * SP];

    const int tid = threadIdx.x;
    const int n0 = blockIdx.x * 128, m0 = blockIdx.y * 128;
    const int wave = tid >> 6, lane = tid & 63;
    const int ln = lane & 15, kq = lane >> 4;
    const int mw = (wave >> 1) * 64, nw = (wave & 1) * 64;
    const int sr = tid >> 1, sh = (tid & 1) * 32;   // staging: row, 32-elem k-half

    f32x4 acc[4][4];
#pragma unroll
    for (int i = 0; i < 4; ++i)
#pragma unroll
        for (int j = 0; j < 4; ++j) acc[i][j] = (f32x4){0.f, 0.f, 0.f, 0.f};

    for (int k0 = 0; k0 < 512; k0 += 64) {
        __syncthreads();
        {
            const unsigned short* a = A  + (size_t)(m0 + sr) * 512 + k0 + sh;
            const unsigned short* w = Wb + (size_t)(n0 + sr) * 512 + k0 + sh;
            uint4 a0 = ((const uint4*)a)[0], a1 = ((const uint4*)a)[1],
                  a2 = ((const uint4*)a)[2], a3 = ((const uint4*)a)[3];
            uint4 w0 = ((const uint4*)w)[0], w1 = ((const uint4*)w)[1],
                  w2 = ((const uint4*)w)[2], w3 = ((const uint4*)w)[3];
            unsigned short* da = &sA[sr * SP + sh];
            unsigned short* dw = &sW[sr * SP + sh];
            ((uint4*)da)[0] = a0; ((uint4*)da)[1] = a1;
            *(uint4*)(da + 16) = a2; *(uint4*)(da + 24) = a3;
            ((uint4*)dw)[0] = w0; ((uint4*)dw)[1] = w1;
            *(uint4*)(dw + 16) = w2; *(uint4*)(dw + 24) = w3;
        }
        __syncthreads();

        bf16x8 af[4][2], bf[4][2];
#pragma unroll
        for (int mt = 0; mt < 4; ++mt) {
            const unsigned short* ap = &sA[(mw + mt * 16 + ln) * SP + kq * 8];
            af[mt][0] = *(const bf16x8*)(ap);
            af[mt][1] = *(const bf16x8*)(ap + 32);
        }
#pragma unroll
        for (int nt = 0; nt < 4; ++nt) {
            const unsigned short* bp = &sW[(nw + nt * 16 + ln) * SP + kq * 8];
            bf[nt][0] = *(const bf16x8*)(bp);
            bf[nt][1] = *(const bf16x8*)(bp + 32);
        }
#pragma unroll
        for (int mt = 0; mt < 4; ++mt)
#pragma unroll
            for (int nt = 0; nt < 4; ++nt) {
                acc[mt][nt] = __builtin_amdgcn_mfma_f32_16x16x32_bf16(af[mt][0], bf[nt][0], acc[mt][nt], 0, 0, 0);
                acc[mt][nt] = __builtin_amdgcn_mfma_f32_16x16x32_bf16(af[mt][1], bf[nt][1], acc[mt][nt], 0, 0, 0);
            }
    }

#pragma unroll
    for (int mt = 0; mt < 4; ++mt)
#pragma unroll
        for (int nt = 0; nt < 4; ++nt)
#pragma unroll
            for (int r = 0; r < 4; ++r)
                C[(size_t)(m0 + mw + mt * 16 + kq * 4 + r) * 512 + n0 + nw + nt * 16 + ln] =
                    acc[mt][nt][r];
}

extern "C" void kernel_launch(void* const* d_in, const int* in_sizes, int n_in,
                              void* d_out, int out_size, void* d_ws, size_t ws_size,
                              hipStream_t stream) {
    const float* qpos  = (const float*)d_in[0];
    const float* kpos  = (const float*)d_in[1];
    const float* vals  = (const float*)d_in[2];
    const int*   kmask = (const int*)  d_in[3];
    const float* ls    = (const float*)d_in[4];
    const float* wout  = (const float*)d_in[5];
    float* out = (float*)d_out;

    unsigned short* vals_t   = (unsigned short*)d_ws;                    // 8 MiB
    unsigned short* attended = vals_t + (size_t)4 * 1024 * 1024;         // 8 MiB
    unsigned short* w_bf     = vals_t + (size_t)8 * 1024 * 1024;         // 512 KiB

    cvt_vals<<<dim3(32, HD, BB), 256, 0, stream>>>(vals, vals_t);
    cvt_w   <<<dim3(256), 256, 0, stream>>>(wout, w_bf);
    attend3 <<<dim3(32, 2, BB), 256, 0, stream>>>(qpos, kpos, vals_t, kmask, ls, attended);
    proj3   <<<dim3(4, 64), 256, 0, stream>>>(attended, w_bf, out);
}